// Round 1
// baseline (819.594 us; speedup 1.0000x reference)
//
#include <hip/hip_runtime.h>
#include <hip/hip_fp16.h>

#define T_DIM 2048
#define B_DIM 16
#define D_DIM 1024
#define M_TOT (T_DIM * B_DIM)   // 32768
#define N_TOT (2 * D_DIM)       // 2048 (W_alpha rows then W_x rows)
#define K_TOT D_DIM             // 1024
#define BD    (B_DIM * D_DIM)   // 16384 chains

typedef __attribute__((ext_vector_type(8))) short short8;
typedef __attribute__((ext_vector_type(4))) float floatx4;

__device__ __forceinline__ short f32_to_bf16(float f) {
  unsigned u = __float_as_uint(f);
  u = (u + 0x7FFFu + ((u >> 16) & 1u)) >> 16;   // RNE, no NaN care (inputs are finite)
  return (short)u;
}

// ---------------- cast fp32 -> bf16, 8 elems/thread ----------------
__global__ __launch_bounds__(256) void cast_bf16_k(const float* __restrict__ src,
                                                   short* __restrict__ dst) {
  const size_t i = ((size_t)blockIdx.x * 256 + threadIdx.x) * 8;
  floatx4 f0 = *(const floatx4*)(src + i);
  floatx4 f1 = *(const floatx4*)(src + i + 4);
  short8 o;
  o[0] = f32_to_bf16(f0[0]); o[1] = f32_to_bf16(f0[1]);
  o[2] = f32_to_bf16(f0[2]); o[3] = f32_to_bf16(f0[3]);
  o[4] = f32_to_bf16(f1[0]); o[5] = f32_to_bf16(f1[1]);
  o[6] = f32_to_bf16(f1[2]); o[7] = f32_to_bf16(f1[3]);
  *(short8*)(dst + i) = o;
}

// ---------------- fused dual-GEMM + activation epilogue ----------------
// out[m,n] = sum_k xb[m,k] * wb[n,k];  n<1024 -> alpha=sigmoid(+b_alpha), else v_raw=tanh(+b_v)
// stores fp16 pairs: pairbuf[(m*1024+e)*2 + {0:alpha,1:vraw}]
#define GLDS16(gp, lp)                                                                   \
  __builtin_amdgcn_global_load_lds((const __attribute__((address_space(1))) void*)(gp),  \
                                   (__attribute__((address_space(3))) void*)(lp), 16, 0, 0)

__global__ __launch_bounds__(256, 2) void gemm_act_k(
    const short* __restrict__ xb, const short* __restrict__ wb,
    const float* __restrict__ b_alpha, const float* __restrict__ b_v,
    __half* __restrict__ pairbuf) {
  __shared__ __align__(16) short As[128 * 32];
  __shared__ __align__(16) short Bs[128 * 32];
  const int tid  = threadIdx.x;
  const int wave = tid >> 6;
  const int lane = tid & 63;
  const int quad = lane >> 4;
  const int l16  = lane & 15;
  const int mblk = blockIdx.y << 7;
  const int nblk = blockIdx.x << 7;
  const int wrow = (wave >> 1) << 6;   // wave's 64-row offset in tile
  const int wcol = (wave & 1) << 6;    // wave's 64-col offset in tile

  floatx4 acc[4][4];
#pragma unroll
  for (int i = 0; i < 4; ++i)
#pragma unroll
    for (int j = 0; j < 4; ++j) acc[i][j] = {0.f, 0.f, 0.f, 0.f};

  // staging: 512 16B-chunks per tile; chunk q -> row q>>2, k-chunk q&3
  // instr0 covers chunks [0,256) (q = tid), instr1 chunks [256,512)
  const int chunk_m = tid >> 2;   // 0..63
  const int chunk_c = tid & 3;
  const short* gA0 = xb + (size_t)(mblk + chunk_m) * K_TOT + chunk_c * 8;
  const short* gA1 = gA0 + (size_t)64 * K_TOT;
  const short* gB0 = wb + (size_t)(nblk + chunk_m) * K_TOT + chunk_c * 8;
  const short* gB1 = gB0 + (size_t)64 * K_TOT;
  short* lA0 = As + wave * 512;          // wave-uniform LDS bases (lane*16B appended by HW)
  short* lA1 = As + 2048 + wave * 512;
  short* lB0 = Bs + wave * 512;
  short* lB1 = Bs + 2048 + wave * 512;

  const int aoff = (wrow + l16) * 32 + quad * 8;  // A frag: row wrow+mt*16+l16, k = quad*8..+7
  const int boff = (wcol + l16) * 32 + quad * 8;

  for (int k0 = 0; k0 < K_TOT; k0 += 32) {
    GLDS16(gA0 + k0, lA0);
    GLDS16(gA1 + k0, lA1);
    GLDS16(gB0 + k0, lB0);
    GLDS16(gB1 + k0, lB1);
    __syncthreads();
    short8 af[4], bf[4];
#pragma unroll
    for (int i = 0; i < 4; ++i) af[i] = *(const short8*)(As + aoff + i * 512);
#pragma unroll
    for (int i = 0; i < 4; ++i) bf[i] = *(const short8*)(Bs + boff + i * 512);
#pragma unroll
    for (int i = 0; i < 4; ++i)
#pragma unroll
      for (int j = 0; j < 4; ++j)
        acc[i][j] = __builtin_amdgcn_mfma_f32_16x16x32_bf16(af[i], bf[j], acc[i][j], 0, 0, 0);
    __syncthreads();
  }

  const bool isA = (nblk < D_DIM);          // block-uniform
  const float* __restrict__ bias = isA ? b_alpha : b_v;
  const int hsel = isA ? 0 : 1;
#pragma unroll
  for (int j = 0; j < 4; ++j) {
    const int n_g = nblk + wcol + j * 16 + l16;
    const int e = isA ? n_g : (n_g - D_DIM);
    const float bz = bias[e];
#pragma unroll
    for (int i = 0; i < 4; ++i) {
      const floatx4 v = acc[i][j];
      const int m_base = mblk + wrow + i * 16 + quad * 4;  // D: row = quad*4+reg, col = l16
#pragma unroll
      for (int r = 0; r < 4; ++r) {
        const float z = v[r] + bz;
        float val;
        if (isA) {
          val = __builtin_amdgcn_rcpf(1.f + __expf(-z));            // sigmoid
        } else {
          val = 1.f - 2.f * __builtin_amdgcn_rcpf(__expf(2.f * z) + 1.f);  // tanh
        }
        pairbuf[((size_t)(m_base + r) * D_DIM + e) * 2 + hsel] = __float2half(val);
      }
    }
  }
}

// ---------------- sequential scan: one thread per (b,d) chain ----------------
__global__ __launch_bounds__(64) void scan_k(const __half2* __restrict__ pair,
                                             const float* __restrict__ d_g,
                                             const float* __restrict__ b_g,
                                             float* __restrict__ outbuf) {
  const int c = blockIdx.x * 64 + threadIdx.x;   // chain id = b*D + d
  const float dg = d_g[c & (D_DIM - 1)];
  const float bg = b_g[c & (D_DIM - 1)];
  float* __restrict__ outs = outbuf;                       // [T, B*D]
  float* __restrict__ hout = outbuf + (size_t)T_DIM * BD;  // [T+1, B*D]
  hout[c] = 0.f;                                           // h0
  float h = 0.f;
  size_t idx = c;
  __half2 p = pair[idx];
#pragma unroll 4
  for (int t = 0; t < T_DIM; ++t) {
    const __half2 pn = pair[idx + BD];       // prefetch (last iter reads pad slab)
    const float2 av = __half22float2(p);     // .x = alpha, .y = v_raw
    const float g = __builtin_amdgcn_rcpf(1.f + __expf(dg * fabsf(h) - bg));
    const float v = av.y * g;
    h = fmaf(av.x, h - v, v);                // alpha*h + (1-alpha)*v
    const float s = __builtin_amdgcn_rcpf(1.f + __expf(-h));
    outs[idx] = h * h * s;                   // h * silu(h)
    hout[idx + BD] = h;
    idx += BD;
    p = pn;
  }
}

extern "C" void kernel_launch(void* const* d_in, const int* in_sizes, int n_in,
                              void* d_out, int out_size, void* d_ws, size_t ws_size,
                              hipStream_t stream) {
  const float* x       = (const float*)d_in[0];
  const float* W_alpha = (const float*)d_in[1];
  const float* b_alpha = (const float*)d_in[2];
  const float* d_g     = (const float*)d_in[3];
  const float* b_g     = (const float*)d_in[4];
  const float* W_x     = (const float*)d_in[5];
  const float* b_v     = (const float*)d_in[6];
  float* out = (float*)d_out;

  // ws layout: xb (64MB) | wb (4MB) | pairbuf (128MB + 64KB prefetch pad)
  char* ws = (char*)d_ws;
  short*  xb      = (short*)ws;                                  // [32768][1024] bf16
  short*  wb      = (short*)(ws + (size_t)67108864);             // [2048][1024] bf16
  __half* pairbuf = (__half*)(ws + (size_t)71303168);            // [32768][1024][2] fp16

  cast_bf16_k<<<M_TOT * K_TOT / (8 * 256), 256, 0, stream>>>(x, xb);
  cast_bf16_k<<<D_DIM * K_TOT / (8 * 256), 256, 0, stream>>>(W_alpha, wb);
  cast_bf16_k<<<D_DIM * K_TOT / (8 * 256), 256, 0, stream>>>(W_x, wb + (size_t)D_DIM * K_TOT);
  gemm_act_k<<<dim3(N_TOT / 128, M_TOT / 128), 256, 0, stream>>>(xb, wb, b_alpha, b_v, pairbuf);
  scan_k<<<BD / 64, 64, 0, stream>>>((const __half2*)pairbuf, d_g, b_g, out);
}

// Round 2
// 691.105 us; speedup vs baseline: 1.1859x; 1.1859x over previous
//
#include <hip/hip_runtime.h>
#include <hip/hip_fp16.h>

#define T_DIM 2048
#define B_DIM 16
#define D_DIM 1024
#define M_TOT (T_DIM * B_DIM)   // 32768
#define N_TOT (2 * D_DIM)       // 2048 (W_alpha rows then W_x rows)
#define K_TOT D_DIM             // 1024
#define BD    (B_DIM * D_DIM)   // 16384 chains

typedef __attribute__((ext_vector_type(8))) short short8;
typedef __attribute__((ext_vector_type(4))) float floatx4;

__device__ __forceinline__ short f32_to_bf16(float f) {
  unsigned u = __float_as_uint(f);
  u = (u + 0x7FFFu + ((u >> 16) & 1u)) >> 16;   // RNE, no NaN care (inputs are finite)
  return (short)u;
}

// ---------------- cast fp32 -> bf16, 8 elems/thread ----------------
__global__ __launch_bounds__(256) void cast_bf16_k(const float* __restrict__ src,
                                                   short* __restrict__ dst) {
  const size_t i = ((size_t)blockIdx.x * 256 + threadIdx.x) * 8;
  floatx4 f0 = *(const floatx4*)(src + i);
  floatx4 f1 = *(const floatx4*)(src + i + 4);
  short8 o;
  o[0] = f32_to_bf16(f0[0]); o[1] = f32_to_bf16(f0[1]);
  o[2] = f32_to_bf16(f0[2]); o[3] = f32_to_bf16(f0[3]);
  o[4] = f32_to_bf16(f1[0]); o[5] = f32_to_bf16(f1[1]);
  o[6] = f32_to_bf16(f1[2]); o[7] = f32_to_bf16(f1[3]);
  *(short8*)(dst + i) = o;
}

// ---------------- fused dual-GEMM + activation epilogue ----------------
// out[m,n] = sum_k xb[m,k] * wb[n,k];  n<1024 -> alpha=sigmoid(+b_alpha), else v_raw=tanh(+b_v)
// stores fp16 pairs: pairbuf[(m*1024+e)*2 + {0:alpha,1:vraw}]
#define GLDS16(gp, lp)                                                                   \
  __builtin_amdgcn_global_load_lds((const __attribute__((address_space(1))) void*)(gp),  \
                                   (__attribute__((address_space(3))) void*)(lp), 16, 0, 0)

__global__ __launch_bounds__(256, 2) void gemm_act_k(
    const short* __restrict__ xb, const short* __restrict__ wb,
    const float* __restrict__ b_alpha, const float* __restrict__ b_v,
    __half* __restrict__ pairbuf) {
  __shared__ __align__(16) short As[128 * 32];
  __shared__ __align__(16) short Bs[128 * 32];
  const int tid  = threadIdx.x;
  const int wave = tid >> 6;
  const int lane = tid & 63;
  const int quad = lane >> 4;
  const int l16  = lane & 15;
  const int mblk = blockIdx.y << 7;
  const int nblk = blockIdx.x << 7;
  const int wrow = (wave >> 1) << 6;   // wave's 64-row offset in tile
  const int wcol = (wave & 1) << 6;    // wave's 64-col offset in tile

  floatx4 acc[4][4];
#pragma unroll
  for (int i = 0; i < 4; ++i)
#pragma unroll
    for (int j = 0; j < 4; ++j) acc[i][j] = {0.f, 0.f, 0.f, 0.f};

  // staging: 512 16B-chunks per tile; chunk q -> row q>>2, k-chunk q&3
  const int chunk_m = tid >> 2;   // 0..63
  const int chunk_c = tid & 3;
  const short* gA0 = xb + (size_t)(mblk + chunk_m) * K_TOT + chunk_c * 8;
  const short* gA1 = gA0 + (size_t)64 * K_TOT;
  const short* gB0 = wb + (size_t)(nblk + chunk_m) * K_TOT + chunk_c * 8;
  const short* gB1 = gB0 + (size_t)64 * K_TOT;
  short* lA0 = As + wave * 512;          // wave-uniform LDS bases (lane*16B appended by HW)
  short* lA1 = As + 2048 + wave * 512;
  short* lB0 = Bs + wave * 512;
  short* lB1 = Bs + 2048 + wave * 512;

  const int aoff = (wrow + l16) * 32 + quad * 8;  // A frag: row wrow+mt*16+l16, k = quad*8..+7
  const int boff = (wcol + l16) * 32 + quad * 8;

  for (int k0 = 0; k0 < K_TOT; k0 += 32) {
    GLDS16(gA0 + k0, lA0);
    GLDS16(gA1 + k0, lA1);
    GLDS16(gB0 + k0, lB0);
    GLDS16(gB1 + k0, lB1);
    __syncthreads();
    short8 af[4], bf[4];
#pragma unroll
    for (int i = 0; i < 4; ++i) af[i] = *(const short8*)(As + aoff + i * 512);
#pragma unroll
    for (int i = 0; i < 4; ++i) bf[i] = *(const short8*)(Bs + boff + i * 512);
#pragma unroll
    for (int i = 0; i < 4; ++i)
#pragma unroll
      for (int j = 0; j < 4; ++j)
        acc[i][j] = __builtin_amdgcn_mfma_f32_16x16x32_bf16(af[i], bf[j], acc[i][j], 0, 0, 0);
    __syncthreads();
  }

  const bool isA = (nblk < D_DIM);          // block-uniform
  const float* __restrict__ bias = isA ? b_alpha : b_v;
  const int hsel = isA ? 0 : 1;
#pragma unroll
  for (int j = 0; j < 4; ++j) {
    const int n_g = nblk + wcol + j * 16 + l16;
    const int e = isA ? n_g : (n_g - D_DIM);
    const float bz = bias[e];
#pragma unroll
    for (int i = 0; i < 4; ++i) {
      const floatx4 v = acc[i][j];
      const int m_base = mblk + wrow + i * 16 + quad * 4;  // D: row = quad*4+reg, col = l16
#pragma unroll
      for (int r = 0; r < 4; ++r) {
        const float z = v[r] + bz;
        float val;
        if (isA) {
          val = __builtin_amdgcn_rcpf(1.f + __expf(-z));            // sigmoid
        } else {
          val = 1.f - 2.f * __builtin_amdgcn_rcpf(__expf(2.f * z) + 1.f);  // tanh
        }
        pairbuf[((size_t)(m_base + r) * D_DIM + e) * 2 + hsel] = __float2half(val);
      }
    }
  }
}

// ---------------- sequential scan: one thread per (b,d) chain ----------------
// 8-deep register ring-buffer prefetch: per step issue load for step t+8, so 8
// loads outstanding -> tolerates ~8x per-step-time of memory latency (~360 cyc).
// Critical h-chain (7 dependent ops): abs -> fma(dg') -> exp2 -> add1 -> rcp ->
// mul(w*g) -> fma(alpha*h + .). w=(1-alpha)*vraw hoisted off-path (known 8 steps early).
__global__ __launch_bounds__(64) void scan_k(const __half2* __restrict__ pair,
                                             const float* __restrict__ d_g,
                                             const float* __restrict__ b_g,
                                             float* __restrict__ outbuf) {
  const int c = blockIdx.x * 64 + threadIdx.x;   // chain id = b*D + d
  const float LOG2E = 1.44269504f;
  const float dg = d_g[c & (D_DIM - 1)] * LOG2E;
  const float bg = b_g[c & (D_DIM - 1)] * LOG2E;
  float* __restrict__ outs = outbuf;                       // [T, B*D]
  float* __restrict__ hout = outbuf + (size_t)T_DIM * BD;  // [T+1, B*D]
  hout[c] = 0.f;                                           // h0
  float h = 0.f;
  size_t idx = c;
  __half2 p[8];
#pragma unroll
  for (int k = 0; k < 8; ++k) p[k] = pair[idx + (size_t)k * BD];
  for (int t = 0; t < T_DIM; t += 8) {
    // group-uniform: prefetch targets (t+8 .. t+15) valid iff t+8 < T
    const size_t pfadd = (t + 8 < T_DIM) ? (size_t)8 * BD : 0;
#pragma unroll
    for (int k = 0; k < 8; ++k) {
      const float2 av = __half22float2(p[k]);    // .x = alpha, .y = v_raw
      p[k] = pair[idx + pfadd];                  // prefetch step t+k+8
      const float w = (1.f - av.x) * av.y;       // off critical path
      const float e = __builtin_amdgcn_exp2f(fmaf(dg, fabsf(h), -bg));
      const float g = __builtin_amdgcn_rcpf(1.f + e);
      h = fmaf(av.x, h, w * g);                  // alpha*h + (1-alpha)*v*g
      const float s = __builtin_amdgcn_rcpf(1.f + __builtin_amdgcn_exp2f(-LOG2E * h));
      outs[idx] = h * h * s;                     // h * silu(h)
      hout[idx + BD] = h;
      idx += BD;
    }
  }
}

extern "C" void kernel_launch(void* const* d_in, const int* in_sizes, int n_in,
                              void* d_out, int out_size, void* d_ws, size_t ws_size,
                              hipStream_t stream) {
  const float* x       = (const float*)d_in[0];
  const float* W_alpha = (const float*)d_in[1];
  const float* b_alpha = (const float*)d_in[2];
  const float* d_g     = (const float*)d_in[3];
  const float* b_g     = (const float*)d_in[4];
  const float* W_x     = (const float*)d_in[5];
  const float* b_v     = (const float*)d_in[6];
  float* out = (float*)d_out;

  // ws layout: xb (64MB) | wb (4MB) | pairbuf (128MB)
  char* ws = (char*)d_ws;
  short*  xb      = (short*)ws;                                  // [32768][1024] bf16
  short*  wb      = (short*)(ws + (size_t)67108864);             // [2048][1024] bf16
  __half* pairbuf = (__half*)(ws + (size_t)71303168);            // [32768][1024][2] fp16

  cast_bf16_k<<<M_TOT * K_TOT / (8 * 256), 256, 0, stream>>>(x, xb);
  cast_bf16_k<<<D_DIM * K_TOT / (8 * 256), 256, 0, stream>>>(W_alpha, wb);
  cast_bf16_k<<<D_DIM * K_TOT / (8 * 256), 256, 0, stream>>>(W_x, wb + (size_t)D_DIM * K_TOT);
  gemm_act_k<<<dim3(N_TOT / 128, M_TOT / 128), 256, 0, stream>>>(xb, wb, b_alpha, b_v, pairbuf);
  scan_k<<<BD / 64, 64, 0, stream>>>((const __half2*)pairbuf, d_g, b_g, out);
}

// Round 3
// 673.763 us; speedup vs baseline: 1.2164x; 1.0257x over previous
//
#include <hip/hip_runtime.h>
#include <hip/hip_fp16.h>

#define T_DIM 2048
#define B_DIM 16
#define D_DIM 1024
#define M_TOT (T_DIM * B_DIM)   // 32768
#define N_TOT (2 * D_DIM)       // 2048 (W_alpha rows then W_x rows)
#define K_TOT D_DIM             // 1024
#define BD    (B_DIM * D_DIM)   // 16384 chains

typedef __attribute__((ext_vector_type(8))) short short8;
typedef __attribute__((ext_vector_type(4))) float floatx4;

__device__ __forceinline__ short f32_to_bf16(float f) {
  unsigned u = __float_as_uint(f);
  u = (u + 0x7FFFu + ((u >> 16) & 1u)) >> 16;   // RNE
  return (short)u;
}

// ---------------- cast fp32 -> bf16, 8 elems/thread ----------------
__global__ __launch_bounds__(256) void cast_bf16_k(const float* __restrict__ src,
                                                   short* __restrict__ dst) {
  const size_t i = ((size_t)blockIdx.x * 256 + threadIdx.x) * 8;
  floatx4 f0 = *(const floatx4*)(src + i);
  floatx4 f1 = *(const floatx4*)(src + i + 4);
  short8 o;
  o[0] = f32_to_bf16(f0[0]); o[1] = f32_to_bf16(f0[1]);
  o[2] = f32_to_bf16(f0[2]); o[3] = f32_to_bf16(f0[3]);
  o[4] = f32_to_bf16(f1[0]); o[5] = f32_to_bf16(f1[1]);
  o[6] = f32_to_bf16(f1[2]); o[7] = f32_to_bf16(f1[3]);
  *(short8*)(dst + i) = o;
}

// ---------------- fused dual-GEMM + activation epilogue ----------------
// out[m,n] = sum_k xb[m,k]*wb[n,k]; n<1024 -> alpha=sigmoid(+b_alpha), else v_raw=tanh(+b_v)
// LDS bank-conflict fix: k-chunk column XOR-swizzled by perm(row)=(row&3)^((row>>2)&1).
// Staging permutes the GLOBAL source chunk per lane (LDS dest is HW-pinned to lane*16B;
// same 64B lines -> coalescing unchanged); fragment reads col = quad^perm -> 2-way (free).
#define GLDS16(gp, lp)                                                                   \
  __builtin_amdgcn_global_load_lds((const __attribute__((address_space(1))) void*)(gp),  \
                                   (__attribute__((address_space(3))) void*)(lp), 16, 0, 0)

__global__ __launch_bounds__(256, 2) void gemm_act_k(
    const short* __restrict__ xb, const short* __restrict__ wb,
    const float* __restrict__ b_alpha, const float* __restrict__ b_v,
    __half* __restrict__ pairbuf) {
  __shared__ __align__(16) short As[128 * 32];
  __shared__ __align__(16) short Bs[128 * 32];
  const int tid  = threadIdx.x;
  const int wave = tid >> 6;
  const int lane = tid & 63;
  const int quad = lane >> 4;
  const int l16  = lane & 15;
  const int mblk = blockIdx.y << 7;
  const int nblk = blockIdx.x << 7;
  const int wrow = (wave >> 1) << 6;
  const int wcol = (wave & 1) << 6;

  floatx4 acc[4][4];
#pragma unroll
  for (int i = 0; i < 4; ++i)
#pragma unroll
    for (int j = 0; j < 4; ++j) acc[i][j] = {0.f, 0.f, 0.f, 0.f};

  // staging: row = tid>>2 (instr1: +64), swizzled source k-chunk
  const int chunk_m = tid >> 2;   // 0..63
  const int c_swz   = (tid & 3) ^ (chunk_m & 3) ^ ((chunk_m >> 2) & 1);
  const short* gA0 = xb + (size_t)(mblk + chunk_m) * K_TOT + c_swz * 8;
  const short* gA1 = gA0 + (size_t)64 * K_TOT;
  const short* gB0 = wb + (size_t)(nblk + chunk_m) * K_TOT + c_swz * 8;
  const short* gB1 = gB0 + (size_t)64 * K_TOT;
  short* lA0 = As + wave * 512;
  short* lA1 = As + 2048 + wave * 512;
  short* lB0 = Bs + wave * 512;
  short* lB1 = Bs + 2048 + wave * 512;

  // fragment read: row = wrow/wcol + i*16 + l16; perm(row) == perm(l16) (base mult of 16)
  const int pl   = (l16 & 3) ^ ((l16 >> 2) & 1);
  const int aoff = (wrow + l16) * 32 + ((quad ^ pl) * 8);
  const int boff = (wcol + l16) * 32 + ((quad ^ pl) * 8);

  for (int k0 = 0; k0 < K_TOT; k0 += 32) {
    GLDS16(gA0 + k0, lA0);
    GLDS16(gA1 + k0, lA1);
    GLDS16(gB0 + k0, lB0);
    GLDS16(gB1 + k0, lB1);
    __syncthreads();
    short8 af[4], bf[4];
#pragma unroll
    for (int i = 0; i < 4; ++i) af[i] = *(const short8*)(As + aoff + i * 512);
#pragma unroll
    for (int i = 0; i < 4; ++i) bf[i] = *(const short8*)(Bs + boff + i * 512);
#pragma unroll
    for (int i = 0; i < 4; ++i)
#pragma unroll
      for (int j = 0; j < 4; ++j)
        acc[i][j] = __builtin_amdgcn_mfma_f32_16x16x32_bf16(af[i], bf[j], acc[i][j], 0, 0, 0);
    __syncthreads();
  }

  const bool isA = (nblk < D_DIM);          // block-uniform
  const float* __restrict__ bias = isA ? b_alpha : b_v;
  const int hsel = isA ? 0 : 1;
#pragma unroll
  for (int j = 0; j < 4; ++j) {
    const int n_g = nblk + wcol + j * 16 + l16;
    const int e = isA ? n_g : (n_g - D_DIM);
    const float bz = bias[e];
#pragma unroll
    for (int i = 0; i < 4; ++i) {
      const floatx4 v = acc[i][j];
      const int m_base = mblk + wrow + i * 16 + quad * 4;  // D: row = quad*4+reg, col = l16
#pragma unroll
      for (int r = 0; r < 4; ++r) {
        const float z = v[r] + bz;
        float val;
        if (isA) {
          val = __builtin_amdgcn_rcpf(1.f + __expf(-z));                   // sigmoid
        } else {
          val = 1.f - 2.f * __builtin_amdgcn_rcpf(__expf(2.f * z) + 1.f);  // tanh
        }
        pairbuf[((size_t)(m_base + r) * D_DIM + e) * 2 + hsel] = __float2half(val);
      }
    }
  }
}

// ---------------- sequential scan: h-recurrence only, fp16 h out ----------------
// 16-deep register ring prefetch; per step: 1x4B load (prefetched), ~7 VALU, 1x2B store.
__global__ __launch_bounds__(64) void scan_k(const __half2* __restrict__ pair,
                                             const float* __restrict__ d_g,
                                             const float* __restrict__ b_g,
                                             __half* __restrict__ hh) {
  const int c = blockIdx.x * 64 + threadIdx.x;   // chain id = b*D + d
  const float LOG2E = 1.44269504f;
  const float dg = d_g[c & (D_DIM - 1)] * LOG2E;
  const float bg = b_g[c & (D_DIM - 1)] * LOG2E;
  hh[c] = __float2half(0.f);                     // h0
  float h = 0.f;
  size_t idx = c;
  __half2 p[16];
#pragma unroll
  for (int k = 0; k < 16; ++k) p[k] = pair[idx + (size_t)k * BD];
  for (int t = 0; t < T_DIM; t += 16) {
    const size_t pfadd = (t + 16 < T_DIM) ? (size_t)16 * BD : 0;
#pragma unroll
    for (int k = 0; k < 16; ++k) {
      const float2 av = __half22float2(p[k]);    // .x = alpha, .y = v_raw
      p[k] = pair[idx + pfadd];                  // prefetch step t+k+16
      const float w = (1.f - av.x) * av.y;       // off critical path
      const float e = __builtin_amdgcn_exp2f(fmaf(dg, fabsf(h), -bg));
      const float g = __builtin_amdgcn_rcpf(1.f + e);
      h = fmaf(av.x, h, w * g);                  // alpha*h + (1-alpha)*v*g
      hh[idx + BD] = __float2half(h);
      idx += BD;
    }
  }
}

// ---------------- parallel epilogue: expand h fp16->fp32, out = h^2 * sigmoid(h) ----
__global__ __launch_bounds__(256) void silu_k(const __half* __restrict__ hh,
                                              float* __restrict__ outbuf) {
  const float LOG2E = 1.44269504f;
  const size_t i = ((size_t)blockIdx.x * 256 + threadIdx.x) * 8;  // i < (T+1)*BD
  float* __restrict__ outs = outbuf;                       // [T, B*D]
  float* __restrict__ hout = outbuf + (size_t)T_DIM * BD;  // [T+1, B*D]
  const __half2* hp = (const __half2*)(hh + i);
  float hf[8];
#pragma unroll
  for (int j = 0; j < 4; ++j) {
    const float2 f = __half22float2(hp[j]);
    hf[2 * j] = f.x; hf[2 * j + 1] = f.y;
  }
  *(floatx4*)(hout + i)     = floatx4{hf[0], hf[1], hf[2], hf[3]};
  *(floatx4*)(hout + i + 4) = floatx4{hf[4], hf[5], hf[6], hf[7]};
  if (i >= BD) {                                           // block-uniform (BD = 8 blocks)
    float o[8];
#pragma unroll
    for (int j = 0; j < 8; ++j) {
      const float s = __builtin_amdgcn_rcpf(1.f + __builtin_amdgcn_exp2f(-LOG2E * hf[j]));
      o[j] = hf[j] * hf[j] * s;                            // h * silu(h)
    }
    *(floatx4*)(outs + i - BD)     = floatx4{o[0], o[1], o[2], o[3]};
    *(floatx4*)(outs + i - BD + 4) = floatx4{o[4], o[5], o[6], o[7]};
  }
}

extern "C" void kernel_launch(void* const* d_in, const int* in_sizes, int n_in,
                              void* d_out, int out_size, void* d_ws, size_t ws_size,
                              hipStream_t stream) {
  const float* x       = (const float*)d_in[0];
  const float* W_alpha = (const float*)d_in[1];
  const float* b_alpha = (const float*)d_in[2];
  const float* d_g     = (const float*)d_in[3];
  const float* b_g     = (const float*)d_in[4];
  const float* W_x     = (const float*)d_in[5];
  const float* b_v     = (const float*)d_in[6];
  float* out = (float*)d_out;

  // ws layout: xb (64MB) | wb (4MB) | pairbuf (128MB). h_half (67.1MB) ALIASES
  // xb+wb (68MB) — xb/wb are dead after gemm_act_k, scan_k writes h_half after.
  char* ws = (char*)d_ws;
  short*  xb      = (short*)ws;                                  // [32768][1024] bf16
  short*  wb      = (short*)(ws + (size_t)67108864);             // [2048][1024] bf16
  __half* pairbuf = (__half*)(ws + (size_t)71303168);            // [32768][1024][2] fp16
  __half* h_half  = (__half*)ws;                                 // [2049][16384] fp16

  cast_bf16_k<<<M_TOT * K_TOT / (8 * 256), 256, 0, stream>>>(x, xb);
  cast_bf16_k<<<D_DIM * K_TOT / (8 * 256), 256, 0, stream>>>(W_alpha, wb);
  cast_bf16_k<<<D_DIM * K_TOT / (8 * 256), 256, 0, stream>>>(W_x, wb + (size_t)D_DIM * K_TOT);
  gemm_act_k<<<dim3(N_TOT / 128, M_TOT / 128), 256, 0, stream>>>(xb, wb, b_alpha, b_v, pairbuf);
  scan_k<<<BD / 64, 64, 0, stream>>>((const __half2*)pairbuf, d_g, b_g, h_half);
  silu_k<<<(T_DIM + 1) * BD / (8 * 256), 256, 0, stream>>>(h_half, out);
}